// Round 7
// baseline (140.504 us; speedup 1.0000x reference)
//
#include <hip/hip_runtime.h>

// Problem constants (B,C,H,W = 2,64,48,48; nh=8 -> d=8, L=2304)
#define LL   2304
#define CCH  64
#define NHD  8

static constexpr float QSCALE = 0.35355339059327373f;  // 8^-0.5
static constexpr float LOG2E  = 1.4426950408889634f;

typedef _Float16 half2_t  __attribute__((ext_vector_type(2)));
typedef _Float16 half4_t  __attribute__((ext_vector_type(4)));
typedef _Float16 half8_t  __attribute__((ext_vector_type(8)));
typedef float    float16_t __attribute__((ext_vector_type(16)));

__device__ __forceinline__ half2_t pk_f16(float a, float b) {
    return __builtin_bit_cast(half2_t, __builtin_amdgcn_cvt_pkrtz(a, b));
}

// v_mfma_f32_32x32x8_f16 lane maps (K=8):
//   A[m = lane&31][k = (lane>>5)*4 + j]   (half4 per lane)
//   B[k = (lane>>5)*4 + j][n = lane&31]
//   C/D: col = lane&31, row = (reg&3) + 8*(reg>>2) + 4*(lane>>5)
// => C reg-quad g of one MFMA == B operand (k-chunk [8g,8g+8)) of the next.

// ---------------------------------------------------------------------------
// Kernel 1: q/k/v = conv1x1(x, W*, b*).  Writes scaled q (f32) to d_out, and
// Q' (pre-scaled by log2e), K, V as f16 rows [bh][l][8] to workspace.
// grid (72 ltiles of 32, B, 3 mats), block 256 = 32 l x 8 heads.
// ---------------------------------------------------------------------------
__global__ __launch_bounds__(256) void k_qkv(
    const float* __restrict__ x,
    const float* __restrict__ Wq, const float* __restrict__ bq,
    const float* __restrict__ Wk, const float* __restrict__ bk,
    const float* __restrict__ Wv, const float* __restrict__ bv,
    float* __restrict__ qout,
    _Float16* __restrict__ Qt, _Float16* __restrict__ Kt, _Float16* __restrict__ Vt)
{
    __shared__ float xs[64][32];
    __shared__ float wsm[64][64];
    const int t   = threadIdx.x;
    const int l0  = blockIdx.x * 32;
    const int b   = blockIdx.y;
    const int mat = blockIdx.z;
    const float* W    = (mat == 0) ? Wq : (mat == 1 ? Wk : Wv);
    const float* bias = (mat == 0) ? bq : (mat == 1 ? bk : bv);
    const float* xb = x + (long)b * CCH * LL;

    #pragma unroll
    for (int p = 0; p < 2; ++p) {
        int flat = (p * 256 + t) * 4;
        int c = flat >> 5, l = flat & 31;
        *(float4*)&xs[c][l] = *(const float4*)&xb[(long)c * LL + l0 + l];
    }
    #pragma unroll
    for (int p = 0; p < 4; ++p) {
        int flat = (p * 256 + t) * 4;
        int c = flat >> 6, l = flat & 63;
        *(float4*)&wsm[c][l] = *(const float4*)&W[flat];
    }
    __syncthreads();

    const int l  = t & 31;
    const int cg = t >> 5;  // head 0..7
    float acc[8];
    #pragma unroll
    for (int j = 0; j < 8; ++j) acc[j] = 0.f;
    for (int cp = 0; cp < 64; ++cp) {
        float xv = xs[cp][l];
        #pragma unroll
        for (int j = 0; j < 8; ++j) acc[j] = fmaf(wsm[cg * 8 + j][cp], xv, acc[j]);
    }
    long row = (long)(b * NHD + cg) * LL + l0 + l;   // [bh][l] row, 8 f16 each
    if (mat == 0) {
        half8_t pq;
        #pragma unroll
        for (int j = 0; j < 8; ++j) {
            float qv = (acc[j] + bias[cg * 8 + j]) * QSCALE;
            qout[((long)b * CCH + cg * 8 + j) * LL + l0 + l] = qv;
            pq[j] = (_Float16)(qv * LOG2E);
        }
        *(half8_t*)(Qt + row * 8) = pq;
    } else if (mat == 1) {
        half8_t pk;
        #pragma unroll
        for (int j = 0; j < 8; ++j) pk[j] = (_Float16)(acc[j] + bias[cg * 8 + j]);
        *(half8_t*)(Kt + row * 8) = pk;
    } else {
        half8_t pv;
        #pragma unroll
        for (int j = 0; j < 8; ++j) pv[j] = (_Float16)(acc[j] + bias[cg * 8 + j]);
        *(half8_t*)(Vt + row * 8) = pv;
    }
}

// ---------------------------------------------------------------------------
// Kernel 2: D[k] = sum_q 2^(Q'[q].K[k]) via MFMA S^T tiles; epilogue writes
// V2[bh][c][k] = V[k][c] * 256/D[k]  (f16, transposed for k_av's A operand).
// grid (72 ktiles of 32, 16 bh), block 256 = 4 waves, each a disjoint q range.
// Barrier-free hot loop: qB loaded straight from global (L2-hot), no LDS.
// ---------------------------------------------------------------------------
__global__ __launch_bounds__(256) void k_denom(
    const _Float16* __restrict__ Qt, const _Float16* __restrict__ Kt,
    const _Float16* __restrict__ Vt, _Float16* __restrict__ V2)
{
    __shared__ float Dp[4][32];
    __shared__ float rDs[32];
    const int t    = threadIdx.x;
    const int bh   = blockIdx.y;
    const int k0   = blockIdx.x * 32;
    const int lane = t & 63, w = t >> 6;
    const int half = lane >> 5, l31 = lane & 31;

    // fixed A operand: K-tile rows k0..k0+31
    half4_t kA = *(const half4_t*)(Kt + ((long)bh * LL + k0 + l31) * 8 + half * 4);

    // wave w owns q in [w*576, (w+1)*576): 18 tiles of 32
    const _Float16* qb = Qt + ((long)bh * LL + w * 576 + l31) * 8 + half * 4;

    float16_t D0 = {}, D1 = {};
    #pragma unroll 2
    for (int qt = 0; qt < 18; ++qt) {
        half4_t qB = *(const half4_t*)(qb + (long)qt * 32 * 8);
        float16_t S = __builtin_amdgcn_mfma_f32_32x32x8f16(kA, qB, (float16_t){}, 0, 0, 0);
        if (qt & 1) {
            #pragma unroll
            for (int r = 0; r < 16; ++r) D1[r] += __builtin_amdgcn_exp2f(S[r]);
        } else {
            #pragma unroll
            for (int r = 0; r < 16; ++r) D0[r] += __builtin_amdgcn_exp2f(S[r]);
        }
    }
    // reduce over q-cols (lanes within each 32-half)
    #pragma unroll
    for (int r = 0; r < 16; ++r) {
        float v = D0[r] + D1[r];
        v += __shfl_xor(v, 1);  v += __shfl_xor(v, 2);  v += __shfl_xor(v, 4);
        v += __shfl_xor(v, 8);  v += __shfl_xor(v, 16);
        D0[r] = v;
    }
    if (l31 == 0) {
        #pragma unroll
        for (int r = 0; r < 16; ++r) {
            int row = (r & 3) + 8 * (r >> 2) + 4 * half;
            Dp[w][row] = D0[r];
        }
    }
    __syncthreads();
    if (t < 32) rDs[t] = 256.0f / (Dp[0][t] + Dp[1][t] + Dp[2][t] + Dp[3][t]);
    __syncthreads();
    {   // V2[bh][c][k0+kk] = V[k0+kk][c] * rDs[kk]
        int kk = t >> 3, c = t & 7;
        float v = (float)Vt[((long)bh * LL + k0 + kk) * 8 + c];
        V2[((long)bh * 8 + c) * LL + k0 + kk] = (_Float16)(v * rDs[kk]);
    }
}

// ---------------------------------------------------------------------------
// Kernel 3: O'[c,q] = sum_k V2[c,k] * 2^(Q'[q].K[k]); S^T C-regs feed PV MFMA
// as B operand quad-by-quad.  Barrier-free: kA/vA fragments loaded straight
// from global (all 4 waves share lines -> L1 broadcast).  6 k-splits -> slabs.
// grid (18 q-blocks of 128, 16 bh, 6 ksplits), block 256 = 4 waves x 32 q.
// ---------------------------------------------------------------------------
__global__ __launch_bounds__(256) void k_av(
    const _Float16* __restrict__ Qt, const _Float16* __restrict__ Kt,
    const _Float16* __restrict__ V2, float* __restrict__ ot)
{
    const int t    = threadIdx.x;
    const int bh   = blockIdx.y;
    const int s    = blockIdx.z;
    const int b = bh >> 3, h = bh & 7;
    const int lane = t & 63, w = t >> 6;
    const int half = lane >> 5, l31 = lane & 31;
    const int q0   = blockIdx.x * 128 + w * 32;
    const int cl   = l31 & 7;   // c-row (lanes 8..31 duplicate; D rows >=8 unused)

    // fixed B operand: Q-tile cols q0..q0+31
    half4_t qB = *(const half4_t*)(Qt + ((long)bh * LL + q0 + l31) * 8 + half * 4);

    const _Float16* kp = Kt + ((long)bh * LL + s * 384 + l31) * 8 + half * 4;
    const _Float16* vp = V2 + ((long)bh * 8 + cl) * LL + s * 384 + half * 4;

    float16_t O0 = {}, O1 = {};
    #pragma unroll 2
    for (int kt = 0; kt < 12; ++kt) {
        half4_t kA  = *(const half4_t*)(kp + (long)kt * 32 * 8);
        half4_t vA0 = *(const half4_t*)(vp + kt * 32 + 0);
        half4_t vA1 = *(const half4_t*)(vp + kt * 32 + 8);
        half4_t vA2 = *(const half4_t*)(vp + kt * 32 + 16);
        half4_t vA3 = *(const half4_t*)(vp + kt * 32 + 24);
        float16_t S = __builtin_amdgcn_mfma_f32_32x32x8f16(kA, qB, (float16_t){}, 0, 0, 0);
        #pragma unroll
        for (int g = 0; g < 4; ++g) {
            half2_t p0 = pk_f16(__builtin_amdgcn_exp2f(S[4 * g + 0]),
                                __builtin_amdgcn_exp2f(S[4 * g + 1]));
            half2_t p1 = pk_f16(__builtin_amdgcn_exp2f(S[4 * g + 2]),
                                __builtin_amdgcn_exp2f(S[4 * g + 3]));
            half4_t pB = __builtin_shufflevector(p0, p1, 0, 1, 2, 3);
            half4_t vA = (g == 0) ? vA0 : (g == 1) ? vA1 : (g == 2) ? vA2 : vA3;
            if (g & 1) O1 = __builtin_amdgcn_mfma_f32_32x32x8f16(vA, pB, O1, 0, 0, 0);
            else       O0 = __builtin_amdgcn_mfma_f32_32x32x8f16(vA, pB, O0, 0, 0, 0);
        }
    }
    // rows c<8 live in regs 0..3: c = r + 4*half; col q = l31
    float* otb = ot + (long)s * (2 * CCH * LL) + ((long)b * CCH + h * 8) * LL;
    #pragma unroll
    for (int r = 0; r < 4; ++r) {
        int c = r + 4 * half;
        otb[(long)c * LL + q0 + l31] = (O0[r] + O1[r]) * (1.0f / 256.0f);
    }
}

// ---------------------------------------------------------------------------
// Kernel 4: out = Wo . (sum of 6 ot slabs) + bo
// grid (72 ltiles of 32, B), block 256 = 32 l x 8 cgroups of 8 co.
// ---------------------------------------------------------------------------
__global__ __launch_bounds__(256) void k_out(
    const float* __restrict__ ot, const float* __restrict__ Wo,
    const float* __restrict__ bo, float* __restrict__ out)
{
    __shared__ float os[64][32];
    __shared__ float wsm[64][64];
    const int t  = threadIdx.x;
    const int l0 = blockIdx.x * 32;
    const int b  = blockIdx.y;
    const long SLAB = 2 * CCH * (long)LL;
    const float* ob = ot + (long)b * CCH * LL;

    #pragma unroll
    for (int p = 0; p < 2; ++p) {
        int flat = (p * 256 + t) * 4;
        int cv = flat >> 5, l = flat & 31;
        long off = (long)cv * LL + l0 + l;
        float4 a = *(const float4*)&ob[off];
        #pragma unroll
        for (int s = 1; s < 6; ++s) {
            float4 bb = *(const float4*)&ob[s * SLAB + off];
            a.x += bb.x; a.y += bb.y; a.z += bb.z; a.w += bb.w;
        }
        *(float4*)&os[cv][l] = a;
    }
    #pragma unroll
    for (int p = 0; p < 4; ++p) {
        int flat = (p * 256 + t) * 4;
        int c = flat >> 6, l = flat & 63;
        *(float4*)&wsm[c][l] = *(const float4*)&Wo[flat];
    }
    __syncthreads();

    const int l  = t & 31;
    const int cg = t >> 5;
    float acc[8];
    #pragma unroll
    for (int j = 0; j < 8; ++j) acc[j] = 0.f;
    for (int cv = 0; cv < 64; ++cv) {
        float xv = os[cv][l];
        #pragma unroll
        for (int j = 0; j < 8; ++j) acc[j] = fmaf(wsm[cg * 8 + j][cv], xv, acc[j]);
    }
    #pragma unroll
    for (int j = 0; j < 8; ++j) {
        int co = cg * 8 + j;
        out[((long)b * CCH + co) * LL + l0 + l] = acc[j] + bo[co];
    }
}

// ---------------------------------------------------------------------------
extern "C" void kernel_launch(void* const* d_in, const int* in_sizes, int n_in,
                              void* d_out, int out_size, void* d_ws, size_t ws_size,
                              hipStream_t stream)
{
    const float* x  = (const float*)d_in[0];
    const float* Wq = (const float*)d_in[1];
    const float* bq = (const float*)d_in[2];
    const float* Wk = (const float*)d_in[3];
    const float* bk = (const float*)d_in[4];
    const float* Wv = (const float*)d_in[5];
    const float* bv = (const float*)d_in[6];
    const float* Wo = (const float*)d_in[7];
    const float* bo = (const float*)d_in[8];

    float* out  = (float*)d_out;          // [2][64][2304]
    float* qout = out + 294912;           // second tuple output: scaled q

    // ws: 4 f16 buffers (576KB ea) + 6 f32 ot slabs (7.1MB) = ~9.4 MB
    _Float16* Qt = (_Float16*)d_ws;       // [16][2304][8] f16, * log2e*d^-0.5
    _Float16* Kt = Qt + 294912;           // [16][2304][8] f16
    _Float16* Vt = Kt + 294912;           // [16][2304][8] f16 (raw V)
    _Float16* V2 = Vt + 294912;           // [16][8][2304] f16 = V^T * 256/D
    float*    ot = (float*)(V2 + 294912); // [6][2][64][2304] f32 partial slabs

    k_qkv  <<<dim3(72, 2, 3),  256, 0, stream>>>(x, Wq, bq, Wk, bk, Wv, bv, qout, Qt, Kt, Vt);
    k_denom<<<dim3(72, 16),    256, 0, stream>>>(Qt, Kt, Vt, V2);
    k_av   <<<dim3(18, 16, 6), 256, 0, stream>>>(Qt, Kt, V2, ot);
    k_out  <<<dim3(72, 2),     256, 0, stream>>>(ot, Wo, bo, out);
}

// Round 8
// 112.415 us; speedup vs baseline: 1.2499x; 1.2499x over previous
//
#include <hip/hip_runtime.h>

// Problem constants (B,C,H,W = 2,64,48,48; nh=8 -> d=8, L=2304)
#define LL   2304
#define CCH  64
#define NHD  8

static constexpr float QSCALE = 0.35355339059327373f;  // 8^-0.5
static constexpr float LOG2E  = 1.4426950408889634f;

typedef _Float16 half2_t  __attribute__((ext_vector_type(2)));
typedef _Float16 half4_t  __attribute__((ext_vector_type(4)));
typedef _Float16 half8_t  __attribute__((ext_vector_type(8)));
typedef float    float16_t __attribute__((ext_vector_type(16)));

__device__ __forceinline__ half2_t pk_f16(float a, float b) {
    return __builtin_bit_cast(half2_t, __builtin_amdgcn_cvt_pkrtz(a, b));
}

// v_mfma_f32_32x32x8_f16 lane maps (K=8):
//   A[m = lane&31][k = (lane>>5)*4 + j]   (half4 per lane)
//   B[k = (lane>>5)*4 + j][n = lane&31]
//   C/D: col = lane&31, row = (reg&3) + 8*(reg>>2) + 4*(lane>>5)
// => C reg-quad g of one MFMA == B operand (k-chunk [8g,8g+8)) of the next.

// ---------------------------------------------------------------------------
// Kernel 1: q/k/v = conv1x1(x, W*, b*).  Writes scaled q (f32) to d_out, and
// Q' (pre-scaled by log2e), K, V as f16 rows [bh][l][8] to workspace.
// grid (72 ltiles of 32, B, 3 mats), block 256 = 32 l x 8 heads.
// ---------------------------------------------------------------------------
__global__ __launch_bounds__(256) void k_qkv(
    const float* __restrict__ x,
    const float* __restrict__ Wq, const float* __restrict__ bq,
    const float* __restrict__ Wk, const float* __restrict__ bk,
    const float* __restrict__ Wv, const float* __restrict__ bv,
    float* __restrict__ qout,
    _Float16* __restrict__ Qt, _Float16* __restrict__ Kt, _Float16* __restrict__ Vt)
{
    __shared__ float xs[64][32];
    __shared__ float wsm[64][64];
    const int t   = threadIdx.x;
    const int l0  = blockIdx.x * 32;
    const int b   = blockIdx.y;
    const int mat = blockIdx.z;
    const float* W    = (mat == 0) ? Wq : (mat == 1 ? Wk : Wv);
    const float* bias = (mat == 0) ? bq : (mat == 1 ? bk : bv);
    const float* xb = x + (long)b * CCH * LL;

    #pragma unroll
    for (int p = 0; p < 2; ++p) {
        int flat = (p * 256 + t) * 4;
        int c = flat >> 5, l = flat & 31;
        *(float4*)&xs[c][l] = *(const float4*)&xb[(long)c * LL + l0 + l];
    }
    #pragma unroll
    for (int p = 0; p < 4; ++p) {
        int flat = (p * 256 + t) * 4;
        int c = flat >> 6, l = flat & 63;
        *(float4*)&wsm[c][l] = *(const float4*)&W[flat];
    }
    __syncthreads();

    const int l  = t & 31;
    const int cg = t >> 5;  // head 0..7
    float acc[8];
    #pragma unroll
    for (int j = 0; j < 8; ++j) acc[j] = 0.f;
    for (int cp = 0; cp < 64; ++cp) {
        float xv = xs[cp][l];
        #pragma unroll
        for (int j = 0; j < 8; ++j) acc[j] = fmaf(wsm[cg * 8 + j][cp], xv, acc[j]);
    }
    long row = (long)(b * NHD + cg) * LL + l0 + l;   // [bh][l] row, 8 f16 each
    if (mat == 0) {
        half8_t pq;
        #pragma unroll
        for (int j = 0; j < 8; ++j) {
            float qv = (acc[j] + bias[cg * 8 + j]) * QSCALE;
            qout[((long)b * CCH + cg * 8 + j) * LL + l0 + l] = qv;
            pq[j] = (_Float16)(qv * LOG2E);
        }
        *(half8_t*)(Qt + row * 8) = pq;
    } else if (mat == 1) {
        half8_t pk;
        #pragma unroll
        for (int j = 0; j < 8; ++j) pk[j] = (_Float16)(acc[j] + bias[cg * 8 + j]);
        *(half8_t*)(Kt + row * 8) = pk;
    } else {
        half8_t pv;
        #pragma unroll
        for (int j = 0; j < 8; ++j) pv[j] = (_Float16)(acc[j] + bias[cg * 8 + j]);
        *(half8_t*)(Vt + row * 8) = pv;
    }
}

// ---------------------------------------------------------------------------
// Kernel 2: D[k] = sum_q 2^(Q'[q].K[k]) via MFMA S^T tiles; epilogue writes
// V2[bh][c][k] = V[k][c] * 256/D[k]  (f16, transposed for k_av's A operand).
// grid (72 ktiles of 32, 16 bh), block 256 = 4 waves, each a disjoint q range.
// FULL unroll: 18 independent qB loads hoisted by the scheduler (reg prefetch).
// ---------------------------------------------------------------------------
__global__ __launch_bounds__(256) void k_denom(
    const _Float16* __restrict__ Qt, const _Float16* __restrict__ Kt,
    const _Float16* __restrict__ Vt, _Float16* __restrict__ V2)
{
    __shared__ float Dp[4][32];
    __shared__ float rDs[32];
    const int t    = threadIdx.x;
    const int bh   = blockIdx.y;
    const int k0   = blockIdx.x * 32;
    const int lane = t & 63, w = t >> 6;
    const int half = lane >> 5, l31 = lane & 31;

    // fixed A operand: K-tile rows k0..k0+31
    half4_t kA = *(const half4_t*)(Kt + ((long)bh * LL + k0 + l31) * 8 + half * 4);

    // wave w owns q in [w*576, (w+1)*576): 18 tiles of 32
    const _Float16* qb = Qt + ((long)bh * LL + w * 576 + l31) * 8 + half * 4;

    // load all 18 fragments up front (independent of all compute)
    half4_t qf[18];
    #pragma unroll
    for (int qt = 0; qt < 18; ++qt) qf[qt] = *(const half4_t*)(qb + (long)qt * 32 * 8);

    float16_t D0 = {}, D1 = {};
    #pragma unroll
    for (int qt = 0; qt < 18; ++qt) {
        float16_t S = __builtin_amdgcn_mfma_f32_32x32x8f16(kA, qf[qt], (float16_t){}, 0, 0, 0);
        if (qt & 1) {
            #pragma unroll
            for (int r = 0; r < 16; ++r) D1[r] += __builtin_amdgcn_exp2f(S[r]);
        } else {
            #pragma unroll
            for (int r = 0; r < 16; ++r) D0[r] += __builtin_amdgcn_exp2f(S[r]);
        }
    }
    // reduce over q-cols (lanes within each 32-half)
    #pragma unroll
    for (int r = 0; r < 16; ++r) {
        float v = D0[r] + D1[r];
        v += __shfl_xor(v, 1);  v += __shfl_xor(v, 2);  v += __shfl_xor(v, 4);
        v += __shfl_xor(v, 8);  v += __shfl_xor(v, 16);
        D0[r] = v;
    }
    if (l31 == 0) {
        #pragma unroll
        for (int r = 0; r < 16; ++r) {
            int row = (r & 3) + 8 * (r >> 2) + 4 * half;
            Dp[w][row] = D0[r];
        }
    }
    __syncthreads();
    if (t < 32) rDs[t] = 256.0f / (Dp[0][t] + Dp[1][t] + Dp[2][t] + Dp[3][t]);
    __syncthreads();
    {   // V2[bh][c][k0+kk] = V[k0+kk][c] * rDs[kk]
        int kk = t >> 3, c = t & 7;
        float v = (float)Vt[((long)bh * LL + k0 + kk) * 8 + c];
        V2[((long)bh * 8 + c) * LL + k0 + kk] = (_Float16)(v * rDs[kk]);
    }
}

// ---------------------------------------------------------------------------
// Kernel 3: O'[c,q] = sum_k V2[c,k] * 2^(Q'[q].K[k]); S^T C-regs feed PV MFMA
// as B operand quad-by-quad.  Whole 288-key split staged to LDS ONCE (9.3KB,
// one barrier), then a fully-unrolled barrier-free hot loop reads only LDS.
// grid (18 q-blocks of 128, 16 bh, 8 ksplits), block 256 = 4 waves x 32 q.
// ---------------------------------------------------------------------------
#define KSPL 8
#define KSN  288            // keys per split
#define VPAD 296            // lV row stride (f16): spreads c-rows across banks
__global__ __launch_bounds__(256) void k_av(
    const _Float16* __restrict__ Qt, const _Float16* __restrict__ Kt,
    const _Float16* __restrict__ V2, float* __restrict__ ot)
{
    __shared__ _Float16 lK[KSN * 8];      // K rows, 16B each
    __shared__ _Float16 lV[8 * VPAD];     // V2 c-rows, padded stride
    const int t    = threadIdx.x;
    const int bh   = blockIdx.y;
    const int s    = blockIdx.z;
    const int b = bh >> 3, h = bh & 7;
    const int lane = t & 63, w = t >> 6;
    const int half = lane >> 5, l31 = lane & 31;
    const int q0   = blockIdx.x * 128 + w * 32;
    const int cl   = l31 & 7;   // c-row (lanes 8..31 duplicate; D rows >=8 unused)

    // fixed B operand: Q-tile cols q0..q0+31 (independent of staging)
    half4_t qB = *(const half4_t*)(Qt + ((long)bh * LL + q0 + l31) * 8 + half * 4);

    // stage K split: 288 rows x 16B, coalesced
    {
        const float4* kg = (const float4*)(Kt + ((long)bh * LL + s * KSN) * 8);
        for (int r = t; r < KSN; r += 256)
            *(float4*)&lK[r * 8] = kg[r];
        // stage V2 split: 8 c-rows x 288 f16 (36 float4 per row)
        const _Float16* vg = V2 + (long)bh * 8 * LL + s * KSN;
        for (int i = t; i < 288; i += 256) {
            int c = i / 36, j = i % 36;
            *(float4*)&lV[c * VPAD + j * 8] = *(const float4*)(vg + (long)c * LL + j * 8);
        }
    }
    __syncthreads();

    float16_t O0 = {}, O1 = {};
    #pragma unroll
    for (int kt = 0; kt < 9; ++kt) {
        half4_t kA = *(const half4_t*)&lK[(kt * 32 + l31) * 8 + half * 4];
        float16_t S = __builtin_amdgcn_mfma_f32_32x32x8f16(kA, qB, (float16_t){}, 0, 0, 0);
        #pragma unroll
        for (int g = 0; g < 4; ++g) {
            half2_t p0 = pk_f16(__builtin_amdgcn_exp2f(S[4 * g + 0]),
                                __builtin_amdgcn_exp2f(S[4 * g + 1]));
            half2_t p1 = pk_f16(__builtin_amdgcn_exp2f(S[4 * g + 2]),
                                __builtin_amdgcn_exp2f(S[4 * g + 3]));
            half4_t pB = __builtin_shufflevector(p0, p1, 0, 1, 2, 3);
            half4_t vA = *(const half4_t*)&lV[cl * VPAD + kt * 32 + g * 8 + half * 4];
            if (g & 1) O1 = __builtin_amdgcn_mfma_f32_32x32x8f16(vA, pB, O1, 0, 0, 0);
            else       O0 = __builtin_amdgcn_mfma_f32_32x32x8f16(vA, pB, O0, 0, 0, 0);
        }
    }
    // rows c<8 live in regs 0..3: c = r + 4*half; col q = l31
    float* otb = ot + (long)s * (2 * CCH * LL) + ((long)b * CCH + h * 8) * LL;
    #pragma unroll
    for (int r = 0; r < 4; ++r) {
        int c = r + 4 * half;
        otb[(long)c * LL + q0 + l31] = (O0[r] + O1[r]) * (1.0f / 256.0f);
    }
}

// ---------------------------------------------------------------------------
// Kernel 4: out = Wo . (sum of 8 ot slabs) + bo
// grid (72 ltiles of 32, B), block 256 = 32 l x 8 cgroups of 8 co.
// ---------------------------------------------------------------------------
__global__ __launch_bounds__(256) void k_out(
    const float* __restrict__ ot, const float* __restrict__ Wo,
    const float* __restrict__ bo, float* __restrict__ out)
{
    __shared__ float os[64][32];
    __shared__ float wsm[64][64];
    const int t  = threadIdx.x;
    const int l0 = blockIdx.x * 32;
    const int b  = blockIdx.y;
    const long SLAB = 2 * CCH * (long)LL;
    const float* ob = ot + (long)b * CCH * LL;

    #pragma unroll
    for (int p = 0; p < 2; ++p) {
        int flat = (p * 256 + t) * 4;
        int cv = flat >> 5, l = flat & 31;
        long off = (long)cv * LL + l0 + l;
        float4 a = *(const float4*)&ob[off];
        #pragma unroll
        for (int s = 1; s < KSPL; ++s) {
            float4 bb = *(const float4*)&ob[s * SLAB + off];
            a.x += bb.x; a.y += bb.y; a.z += bb.z; a.w += bb.w;
        }
        *(float4*)&os[cv][l] = a;
    }
    #pragma unroll
    for (int p = 0; p < 4; ++p) {
        int flat = (p * 256 + t) * 4;
        int c = flat >> 6, l = flat & 63;
        *(float4*)&wsm[c][l] = *(const float4*)&Wo[flat];
    }
    __syncthreads();

    const int l  = t & 31;
    const int cg = t >> 5;
    float acc[8];
    #pragma unroll
    for (int j = 0; j < 8; ++j) acc[j] = 0.f;
    for (int cv = 0; cv < 64; ++cv) {
        float xv = os[cv][l];
        #pragma unroll
        for (int j = 0; j < 8; ++j) acc[j] = fmaf(wsm[cg * 8 + j][cv], xv, acc[j]);
    }
    #pragma unroll
    for (int j = 0; j < 8; ++j) {
        int co = cg * 8 + j;
        out[((long)b * CCH + co) * LL + l0 + l] = acc[j] + bo[co];
    }
}

// ---------------------------------------------------------------------------
extern "C" void kernel_launch(void* const* d_in, const int* in_sizes, int n_in,
                              void* d_out, int out_size, void* d_ws, size_t ws_size,
                              hipStream_t stream)
{
    const float* x  = (const float*)d_in[0];
    const float* Wq = (const float*)d_in[1];
    const float* bq = (const float*)d_in[2];
    const float* Wk = (const float*)d_in[3];
    const float* bk = (const float*)d_in[4];
    const float* Wv = (const float*)d_in[5];
    const float* bv = (const float*)d_in[6];
    const float* Wo = (const float*)d_in[7];
    const float* bo = (const float*)d_in[8];

    float* out  = (float*)d_out;          // [2][64][2304]
    float* qout = out + 294912;           // second tuple output: scaled q

    // ws: 4 f16 buffers (576KB ea) + 8 f32 ot slabs (9.4MB) = ~11.7 MB
    _Float16* Qt = (_Float16*)d_ws;       // [16][2304][8] f16, * log2e*d^-0.5
    _Float16* Kt = Qt + 294912;           // [16][2304][8] f16
    _Float16* Vt = Kt + 294912;           // [16][2304][8] f16 (raw V)
    _Float16* V2 = Vt + 294912;           // [16][8][2304] f16 = V^T * 256/D
    float*    ot = (float*)(V2 + 294912); // [8][2][64][2304] f32 partial slabs

    k_qkv  <<<dim3(72, 2, 3),     256, 0, stream>>>(x, Wq, bq, Wk, bk, Wv, bv, qout, Qt, Kt, Vt);
    k_denom<<<dim3(72, 16),       256, 0, stream>>>(Qt, Kt, Vt, V2);
    k_av   <<<dim3(18, 16, KSPL), 256, 0, stream>>>(Qt, Kt, V2, ot);
    k_out  <<<dim3(72, 2),        256, 0, stream>>>(ot, Wo, bo, out);
}